// Round 1
// baseline (145.008 us; speedup 1.0000x reference)
//
#include <hip/hip_runtime.h>
#include <math.h>

// Problem constants (fixed by setup_inputs): B=4, N=2048, C=32
#define NB 4
#define NA 2048
#define NC 32
#define IT 256                  // threads per block
#define UI 2                    // i-atoms per thread (ILP)
#define ITILE (IT * UI)         // 512 i per block
#define NS 64                   // j-splits
#define JT (NA / NS)            // 32 j per block
#define NI (NA / ITILE)         // 4 i-tiles
#define NBLK (NS * NI * NB)     // 1024 blocks

static constexpr float CONV001 = 3.3207156f;   // 332.07156 * 0.01

// ws layout (floats) — every slot written each launch (poison-safe):
//   [0, 1024)      pair partial slots, slot = (b*NI + y)*NS + s
//   [1024, 1040)   self partial slots, slot = b*NI + y
#define WS_PAIR 0
#define WS_SELF NBLK

// Last-block-done counter. Device global (zero at module load); the block
// that observes old == NBLK-1 resets it to 0 before the kernel ends, so the
// invariant "counter == 0 at launch" holds across every graph replay.
__device__ int g_counter = 0;

__global__ void __launch_bounds__(IT)
fused_kernel(const float* __restrict__ X,
             const float* __restrict__ embs,
             const float* __restrict__ qs,
             const float* __restrict__ born,
             const float* __restrict__ die,
             const float* __restrict__ sf,
             float* __restrict__ ws,
             float* __restrict__ out) {
    const int t  = threadIdx.x;
    const int s  = blockIdx.x;               // j-split
    const int y  = blockIdx.y;               // i-tile
    const int b  = blockIdx.z;               // batch
    const int i0 = b * NA + y * ITILE;
    const int j0 = b * NA + s * JT;
    const int lane = t & 63;
    const int w    = t >> 6;

    __shared__ float4 jd[JT];                // {x, y, z, s_j}
    __shared__ float  wsum[IT / 64];
    __shared__ float  ssum[IT / 64];
    __shared__ int    lastflag;

    // ---- j-atom data: recompute s_j from embs (L2-resident, 1 MB total) ----
    if (t < JT) {
        const int a = j0 + t;
        const float4* e4 = (const float4*)(embs + (size_t)a * NC);
        float sj = 0.f;
        #pragma unroll
        for (int c = 0; c < NC / 4; ++c) {
            float4 ev = e4[c];
            sj = fmaf(ev.x, sf[NC + 4 * c + 0], fmaf(ev.y, sf[NC + 4 * c + 1],
                 fmaf(ev.z, sf[NC + 4 * c + 2], fmaf(ev.w, sf[NC + 4 * c + 3], sj))));
        }
        jd[t] = make_float4(X[a * 3 + 0], X[a * 3 + 1], X[a * 3 + 2], sj);
    }

    // ---- i-atom data: recompute s_i (2 atoms per thread) ----
    float4 id[UI];
    #pragma unroll
    for (int u = 0; u < UI; ++u) {
        const int a = i0 + u * IT + t;
        const float4* e4 = (const float4*)(embs + (size_t)a * NC);
        float si = 0.f;
        #pragma unroll
        for (int c = 0; c < NC / 4; ++c) {
            float4 ev = e4[c];
            si = fmaf(ev.x, sf[4 * c + 0], fmaf(ev.y, sf[4 * c + 1],
                 fmaf(ev.z, sf[4 * c + 2], fmaf(ev.w, sf[4 * c + 3], si))));
        }
        id[u] = make_float4(X[a * 3 + 0], X[a * 3 + 1], X[a * 3 + 2], si);
    }
    __syncthreads();

    // ---- N^2 pair loop: E_pair ~= rsqrt(d2)*(si+sj) + wd (wd*N^2 closed form) ----
    float acc[UI] = {0.f, 0.f};
    #pragma unroll 4
    for (int jj = 0; jj < JT; ++jj) {
        float4 v = jd[jj];
        #pragma unroll
        for (int u = 0; u < UI; ++u) {
            float dx = v.x - id[u].x;
            float dy = v.y - id[u].y;
            float dz = v.z - id[u].z;
            float d2 = fmaf(dx, dx, fmaf(dy, dy, fmaf(dz, dz, 3e-6f)));
            acc[u] = fmaf(__builtin_amdgcn_rsqf(d2), id[u].w + v.w, acc[u]);
        }
    }

    float pa = acc[0] + acc[1];
    #pragma unroll
    for (int off = 32; off > 0; off >>= 1)
        pa += __shfl_down(pa, off, 64);
    if (lane == 0) wsum[w] = pa;

    // ---- self energy: only the 16 j-split-0 blocks (covers all 8192 atoms) ----
    if (s == 0) {
        float eself = 0.f;
        #pragma unroll
        for (int u = 0; u < UI; ++u) {
            const int a = i0 + u * IT + t;
            const float4* e4 = (const float4*)(embs + (size_t)a * NC);
            float ad = 0.f, R = 0.f;
            #pragma unroll
            for (int c = 0; c < NC / 4; ++c) {
                float4 ev = e4[c];
                ad = fmaf(ev.x, die[4 * c + 0], fmaf(ev.y, die[4 * c + 1],
                     fmaf(ev.z, die[4 * c + 2], fmaf(ev.w, die[4 * c + 3], ad))));
                R  = fmaf(ev.x, born[4 * c + 0], fmaf(ev.y, born[4 * c + 1],
                     fmaf(ev.z, born[4 * c + 2], fmaf(ev.w, born[4 * c + 3], R))));
            }
            ad += 1e-6f;
            R  += 1.0f;
            eself += -(1.0f - __builtin_amdgcn_rcpf(ad)) * qs[a]
                     * __builtin_amdgcn_rcpf(R + 1e-6f);
        }
        #pragma unroll
        for (int off = 32; off > 0; off >>= 1)
            eself += __shfl_down(eself, off, 64);
        if (lane == 0) ssum[w] = eself;
    }
    __syncthreads();

    // ---- publish partials + last-block-done arbitration ----
    if (t == 0) {
        const int slot = (b * NI + y) * NS + s;
        __hip_atomic_store(&ws[WS_PAIR + slot],
                           wsum[0] + wsum[1] + wsum[2] + wsum[3],
                           __ATOMIC_RELEASE, __HIP_MEMORY_SCOPE_AGENT);
        if (s == 0)
            __hip_atomic_store(&ws[WS_SELF + b * NI + y],
                               ssum[0] + ssum[1] + ssum[2] + ssum[3],
                               __ATOMIC_RELEASE, __HIP_MEMORY_SCOPE_AGENT);
        int old = __hip_atomic_fetch_add(&g_counter, 1,
                                         __ATOMIC_ACQ_REL, __HIP_MEMORY_SCOPE_AGENT);
        lastflag = (old == NBLK - 1);
    }
    __syncthreads();
    if (!lastflag) return;

    // ---- finalize (runs once, in whichever block finished last) ----
    // wave w handles batch w (IT=256 -> 4 waves = NB). Deterministic order.
    {
        const int bb = w;
        float v = 0.f;
        #pragma unroll
        for (int k = 0; k < 4; ++k)
            v += __hip_atomic_load(&ws[WS_PAIR + bb * (NI * NS) + k * 64 + lane],
                                   __ATOMIC_ACQUIRE, __HIP_MEMORY_SCOPE_AGENT);
        if (lane < NI)
            v += 2.0f * __hip_atomic_load(&ws[WS_SELF + bb * NI + lane],
                                          __ATOMIC_ACQUIRE, __HIP_MEMORY_SCOPE_AGENT);
        #pragma unroll
        for (int off = 32; off > 0; off >>= 1)
            v += __shfl_down(v, off, 64);
        if (lane == 0) {
            const float wd = sf[2 * NC];
            float r = CONV001 * 0.5f * (v + wd * (float)NA * (float)NA);
            out[bb] = isnan(r) ? 1e-6f : r;
        }
        if (t == 0)
            __hip_atomic_store(&g_counter, 0,
                               __ATOMIC_RELAXED, __HIP_MEMORY_SCOPE_AGENT);
    }
}

extern "C" void kernel_launch(void* const* d_in, const int* in_sizes, int n_in,
                              void* d_out, int out_size, void* d_ws, size_t ws_size,
                              hipStream_t stream) {
    const float* X    = (const float*)d_in[0];
    const float* embs = (const float*)d_in[1];
    const float* qs   = (const float*)d_in[2];
    // d_in[3] = paired_mask (all-false; unused by reference math)
    const float* born = (const float*)d_in[4];
    const float* die  = (const float*)d_in[5];
    const float* sf   = (const float*)d_in[6];

    fused_kernel<<<dim3(NS, NI, NB), IT, 0, stream>>>(
        X, embs, qs, born, die, sf, (float*)d_ws, (float*)d_out);
}

// Round 2
// 117.747 us; speedup vs baseline: 1.2315x; 1.2315x over previous
//
#include <hip/hip_runtime.h>
#include <math.h>

// Problem constants (fixed by setup_inputs): B=4, N=2048, C=32
#define NB 4
#define NA 2048
#define NC 32
#define IT 256                  // threads per block
#define UI 2                    // i-atoms per thread (ILP)
#define ITILE (IT * UI)         // 512 i per block
#define NS 64                   // j-splits
#define JT (NA / NS)            // 32 j per block
#define NI (NA / ITILE)         // 4 i-tiles
#define NBLK (NS * NI * NB)     // 1024 blocks

static constexpr float CONV001 = 3.3207156f;   // 332.07156 * 0.01

// ws layout (floats) — every slot written each launch (poison-safe):
//   [0, 1024)       pair partial slots, slot = (b*NI + y)*NS + s
//   [1024, 1040)    self partial slots, slot = b*NI + y
// Cross-block visibility: kernel boundary (implicit device release at end of
// dispatch 1, acquire at start of dispatch 2). NO in-kernel agent-scope
// atomics — on gfx950 those emit per-block buffer_wbl2/buffer_inv (whole-L2
// ops, not cross-XCD coherent otherwise) and cost ~45 us across 1024 blocks.
#define WS_PAIR 0
#define WS_SELF NBLK

// Dispatch 1: per-block s_i/s_j recompute (embs is 1 MB, L2-resident) +
// N^2 pair energy + self energy (j-split-0 blocks only). Plain stores.
__global__ void __launch_bounds__(IT)
fused_main(const float* __restrict__ X,
           const float* __restrict__ embs,
           const float* __restrict__ qs,
           const float* __restrict__ born,
           const float* __restrict__ die,
           const float* __restrict__ sf,
           float* __restrict__ ws) {
    const int t  = threadIdx.x;
    const int s  = blockIdx.x;               // j-split
    const int y  = blockIdx.y;               // i-tile
    const int b  = blockIdx.z;               // batch
    const int i0 = b * NA + y * ITILE;
    const int j0 = b * NA + s * JT;
    const int lane = t & 63;
    const int w    = t >> 6;

    __shared__ float4 jd[JT];                // {x, y, z, s_j}
    __shared__ float  wsum[IT / 64];
    __shared__ float  ssum[IT / 64];

    // ---- j-atom data: recompute s_j from embs ----
    if (t < JT) {
        const int a = j0 + t;
        const float4* e4 = (const float4*)(embs + (size_t)a * NC);
        float sj = 0.f;
        #pragma unroll
        for (int c = 0; c < NC / 4; ++c) {
            float4 ev = e4[c];
            sj = fmaf(ev.x, sf[NC + 4 * c + 0], fmaf(ev.y, sf[NC + 4 * c + 1],
                 fmaf(ev.z, sf[NC + 4 * c + 2], fmaf(ev.w, sf[NC + 4 * c + 3], sj))));
        }
        jd[t] = make_float4(X[a * 3 + 0], X[a * 3 + 1], X[a * 3 + 2], sj);
    }

    // ---- i-atom data: recompute s_i (2 atoms per thread) ----
    float4 id[UI];
    #pragma unroll
    for (int u = 0; u < UI; ++u) {
        const int a = i0 + u * IT + t;
        const float4* e4 = (const float4*)(embs + (size_t)a * NC);
        float si = 0.f;
        #pragma unroll
        for (int c = 0; c < NC / 4; ++c) {
            float4 ev = e4[c];
            si = fmaf(ev.x, sf[4 * c + 0], fmaf(ev.y, sf[4 * c + 1],
                 fmaf(ev.z, sf[4 * c + 2], fmaf(ev.w, sf[4 * c + 3], si))));
        }
        id[u] = make_float4(X[a * 3 + 0], X[a * 3 + 1], X[a * 3 + 2], si);
    }
    __syncthreads();

    // ---- N^2 pair loop: E_pair ~= rsqrt(d2)*(si+sj) + wd (wd*N^2 closed form) ----
    float acc[UI] = {0.f, 0.f};
    #pragma unroll 4
    for (int jj = 0; jj < JT; ++jj) {
        float4 v = jd[jj];
        #pragma unroll
        for (int u = 0; u < UI; ++u) {
            float dx = v.x - id[u].x;
            float dy = v.y - id[u].y;
            float dz = v.z - id[u].z;
            float d2 = fmaf(dx, dx, fmaf(dy, dy, fmaf(dz, dz, 3e-6f)));
            acc[u] = fmaf(__builtin_amdgcn_rsqf(d2), id[u].w + v.w, acc[u]);
        }
    }

    float pa = acc[0] + acc[1];
    #pragma unroll
    for (int off = 32; off > 0; off >>= 1)
        pa += __shfl_down(pa, off, 64);
    if (lane == 0) wsum[w] = pa;

    // ---- self energy: only the 16 j-split-0 blocks (covers all 8192 atoms) ----
    if (s == 0) {
        float eself = 0.f;
        #pragma unroll
        for (int u = 0; u < UI; ++u) {
            const int a = i0 + u * IT + t;
            const float4* e4 = (const float4*)(embs + (size_t)a * NC);
            float ad = 0.f, R = 0.f;
            #pragma unroll
            for (int c = 0; c < NC / 4; ++c) {
                float4 ev = e4[c];
                ad = fmaf(ev.x, die[4 * c + 0], fmaf(ev.y, die[4 * c + 1],
                     fmaf(ev.z, die[4 * c + 2], fmaf(ev.w, die[4 * c + 3], ad))));
                R  = fmaf(ev.x, born[4 * c + 0], fmaf(ev.y, born[4 * c + 1],
                     fmaf(ev.z, born[4 * c + 2], fmaf(ev.w, born[4 * c + 3], R))));
            }
            ad += 1e-6f;
            R  += 1.0f;
            eself += -(1.0f - __builtin_amdgcn_rcpf(ad)) * qs[a]
                     * __builtin_amdgcn_rcpf(R + 1e-6f);
        }
        #pragma unroll
        for (int off = 32; off > 0; off >>= 1)
            eself += __shfl_down(eself, off, 64);
        if (lane == 0) ssum[w] = eself;
    }
    __syncthreads();

    if (t == 0) {
        const int slot = (b * NI + y) * NS + s;
        ws[WS_PAIR + slot] = wsum[0] + wsum[1] + wsum[2] + wsum[3];
        if (s == 0)
            ws[WS_SELF + b * NI + y] = ssum[0] + ssum[1] + ssum[2] + ssum[3];
    }
}

// Dispatch 2: one 1024-thread block; batch b owned by waves 4b..4b+3
// (slot = (b*NI + y)*NS + s = b*256 + y*64 + s).
__global__ void __launch_bounds__(1024)
finalize_kernel(const float* __restrict__ ws,
                const float* __restrict__ sf,
                float* __restrict__ out) {
    int t = threadIdx.x;
    float v = ws[WS_PAIR + t];
    #pragma unroll
    for (int off = 32; off > 0; off >>= 1)
        v += __shfl_down(v, off, 64);
    __shared__ float wsum[16];
    if ((t & 63) == 0) wsum[t >> 6] = v;
    __syncthreads();
    if (t < NB) {
        float pair = wsum[4 * t] + wsum[4 * t + 1]
                   + wsum[4 * t + 2] + wsum[4 * t + 3];
        float self = 0.f;
        #pragma unroll
        for (int k = 0; k < NI; ++k)
            self += ws[WS_SELF + t * NI + k];
        float wd = sf[2 * NC];
        float r = CONV001 * 0.5f * (pair + 2.0f * self
                                    + wd * (float)NA * (float)NA);
        out[t] = isnan(r) ? 1e-6f : r;
    }
}

extern "C" void kernel_launch(void* const* d_in, const int* in_sizes, int n_in,
                              void* d_out, int out_size, void* d_ws, size_t ws_size,
                              hipStream_t stream) {
    const float* X    = (const float*)d_in[0];
    const float* embs = (const float*)d_in[1];
    const float* qs   = (const float*)d_in[2];
    // d_in[3] = paired_mask (all-false; unused by reference math)
    const float* born = (const float*)d_in[4];
    const float* die  = (const float*)d_in[5];
    const float* sf   = (const float*)d_in[6];

    fused_main<<<dim3(NS, NI, NB), IT, 0, stream>>>(
        X, embs, qs, born, die, sf, (float*)d_ws);
    finalize_kernel<<<1, 1024, 0, stream>>>((float*)d_ws, sf, (float*)d_out);
}

// Round 3
// 109.016 us; speedup vs baseline: 1.3302x; 1.0801x over previous
//
#include <hip/hip_runtime.h>
#include <math.h>

// Problem constants (fixed by setup_inputs): B=4, N=2048, C=32
#define NB 4
#define NA 2048
#define NC 32
#define NATOM (NB * NA)         // 8192
#define IT 256                  // threads per block (pair kernel)
#define UI 2                    // i-atoms per thread (ILP)
#define ITILE (IT * UI)         // 512 i per block
#define NS 64                   // j-splits
#define JT (NA / NS)            // 32 j per block
#define NI (NA / ITILE)         // 4
// pair grid = (NS, NI, NB) = 1024 blocks = 4096 waves = 16/CU

static constexpr float CONV001 = 3.3207156f;   // 332.07156 * 0.01

// ws layout (floats) — every slot fully overwritten each call (poison-safe):
//   [0, 32768)        Pi[a] = {x,y,z,s_i}  (8192 float4)
//   [32768, 65536)    Pj[a] = {x,y,z,s_j}  (8192 float4)
//   [65536, 66560)    pair partial slots (1024)
//   [66560, 66592)    self partial slots (32; 8 per batch)
// Cross-block visibility between dispatches comes from the kernel boundary
// (implicit device-scope release/acquire). NO in-kernel agent-scope fences:
// on gfx950 each one is a whole-L2 buffer_wbl2/buffer_inv (L2s not cross-XCD
// coherent) — measured ~45 us of stall across 1024 blocks in round 1.
#define WS_PI   0
#define WS_PJ   32768
#define WS_PAIR 65536
#define WS_SELF 66560

// Pass 1: per-atom scalars + packed position/scalar arrays + E_self partials.
// grid = 32 blocks x 256 (block k covers atoms [256k, 256k+256), batch k/8).
// Each per-atom dot product is computed exactly ONCE here; the N^2 kernel
// then loads 16 B/thread. (Fusing these dots into the pair blocks replicates
// them x64 and measured 8 us slower overall — round 2.)
__global__ void __launch_bounds__(256)
atom_kernel(const float* __restrict__ X,
            const float* __restrict__ embs,
            const float* __restrict__ qs,
            const float* __restrict__ born,
            const float* __restrict__ die,
            const float* __restrict__ sf,
            float* __restrict__ ws) {
    const int a = blockIdx.x * 256 + threadIdx.x;    // global atom id
    const float4* e4 = (const float4*)(embs + (size_t)a * NC);

    float si = 0.f, sj = 0.f, ad = 0.f, R = 0.f;
    #pragma unroll
    for (int c = 0; c < NC / 4; ++c) {
        float4 ev = e4[c];
        si = fmaf(ev.x, sf[4 * c + 0], fmaf(ev.y, sf[4 * c + 1],
             fmaf(ev.z, sf[4 * c + 2], fmaf(ev.w, sf[4 * c + 3], si))));
        sj = fmaf(ev.x, sf[NC + 4 * c + 0], fmaf(ev.y, sf[NC + 4 * c + 1],
             fmaf(ev.z, sf[NC + 4 * c + 2], fmaf(ev.w, sf[NC + 4 * c + 3], sj))));
        ad = fmaf(ev.x, die[4 * c + 0], fmaf(ev.y, die[4 * c + 1],
             fmaf(ev.z, die[4 * c + 2], fmaf(ev.w, die[4 * c + 3], ad))));
        R  = fmaf(ev.x, born[4 * c + 0], fmaf(ev.y, born[4 * c + 1],
             fmaf(ev.z, born[4 * c + 2], fmaf(ev.w, born[4 * c + 3], R))));
    }
    float x = X[a * 3 + 0];
    float y = X[a * 3 + 1];
    float z = X[a * 3 + 2];
    float4* Pi = (float4*)(ws + WS_PI);
    float4* Pj = (float4*)(ws + WS_PJ);
    Pi[a] = make_float4(x, y, z, si);
    Pj[a] = make_float4(x, y, z, sj);

    ad += 1e-6f;
    R  += 1.0f;
    float eself = -(1.0f - __builtin_amdgcn_rcpf(ad)) * qs[a]
                  * __builtin_amdgcn_rcpf(R + 1e-6f);

    // block reduction -> private self slot
    #pragma unroll
    for (int off = 32; off > 0; off >>= 1)
        eself += __shfl_down(eself, off, 64);
    __shared__ float wsum[4];
    int lane = threadIdx.x & 63;
    int w = threadIdx.x >> 6;
    if (lane == 0) wsum[w] = eself;
    __syncthreads();
    if (threadIdx.x == 0)
        ws[WS_SELF + blockIdx.x] = wsum[0] + wsum[1] + wsum[2] + wsum[3];
}

// Pass 2: N^2 pair energy with precomputed packed atom data.
__global__ void __launch_bounds__(IT)
pair_kernel(const float* __restrict__ wsc,
            float* __restrict__ ws) {
    const int b  = blockIdx.z;
    const int t  = threadIdx.x;
    const int i0 = b * NA + blockIdx.y * ITILE;
    const int j0 = b * NA + blockIdx.x * JT;

    const float4* Pi = (const float4*)(wsc + WS_PI);
    const float4* Pj = (const float4*)(wsc + WS_PJ);

    __shared__ float4 jd[JT];   // {x, y, z, s_j}
    if (t < JT)
        jd[t] = Pj[j0 + t];

    float4 id[UI];
    #pragma unroll
    for (int u = 0; u < UI; ++u)
        id[u] = Pi[i0 + u * IT + t];
    __syncthreads();

    float acc[UI] = {0.f, 0.f};
    // E_pair ~= rsqrt(d2)*(si+sj) + wd  (wd*N^2 in closed form at finalize)
    #pragma unroll 4
    for (int jj = 0; jj < JT; ++jj) {
        float4 v = jd[jj];
        #pragma unroll
        for (int u = 0; u < UI; ++u) {
            float dx = v.x - id[u].x;
            float dy = v.y - id[u].y;
            float dz = v.z - id[u].z;
            float d2 = fmaf(dx, dx, fmaf(dy, dy, fmaf(dz, dz, 3e-6f)));
            acc[u] = fmaf(__builtin_amdgcn_rsqf(d2), id[u].w + v.w, acc[u]);
        }
    }

    float a = acc[0] + acc[1];
    #pragma unroll
    for (int off = 32; off > 0; off >>= 1)
        a += __shfl_down(a, off, 64);
    __shared__ float wsum[IT / 64];
    int lane = t & 63;
    int w = t >> 6;
    if (lane == 0) wsum[w] = a;
    __syncthreads();
    if (t == 0) {
        int slot = (b * NI + blockIdx.y) * NS + blockIdx.x;
        ws[WS_PAIR + slot] = wsum[0] + wsum[1] + wsum[2] + wsum[3];
    }
}

// Pass 3: one 1024-thread block; batch b owned by waves 4b..4b+3.
__global__ void __launch_bounds__(1024)
finalize_kernel(const float* __restrict__ ws,
                const float* __restrict__ sf,
                float* __restrict__ out) {
    int t = threadIdx.x;
    float v = ws[WS_PAIR + t];
    #pragma unroll
    for (int off = 32; off > 0; off >>= 1)
        v += __shfl_down(v, off, 64);
    __shared__ float wsum[16];
    if ((t & 63) == 0) wsum[t >> 6] = v;
    __syncthreads();
    if (t < NB) {
        float pair = wsum[4 * t] + wsum[4 * t + 1]
                   + wsum[4 * t + 2] + wsum[4 * t + 3];
        float self = 0.f;
        #pragma unroll
        for (int k = 0; k < 8; ++k)
            self += ws[WS_SELF + t * 8 + k];
        float wd = sf[2 * NC];
        float r = CONV001 * 0.5f * (pair + 2.0f * self
                                    + wd * (float)NA * (float)NA);
        out[t] = isnan(r) ? 1e-6f : r;
    }
}

extern "C" void kernel_launch(void* const* d_in, const int* in_sizes, int n_in,
                              void* d_out, int out_size, void* d_ws, size_t ws_size,
                              hipStream_t stream) {
    const float* X    = (const float*)d_in[0];
    const float* embs = (const float*)d_in[1];
    const float* qs   = (const float*)d_in[2];
    // d_in[3] = paired_mask (all-false; unused by reference math)
    const float* born = (const float*)d_in[4];
    const float* die  = (const float*)d_in[5];
    const float* sf   = (const float*)d_in[6];
    float* ws  = (float*)d_ws;
    float* out = (float*)d_out;

    atom_kernel<<<NATOM / 256, 256, 0, stream>>>(X, embs, qs, born, die, sf, ws);
    pair_kernel<<<dim3(NS, NI, NB), IT, 0, stream>>>(ws, ws);
    finalize_kernel<<<1, 1024, 0, stream>>>(ws, sf, out);
}